// Round 4
// baseline (1372.106 us; speedup 1.0000x reference)
//
#include <hip/hip_runtime.h>
#include <math.h>

#define B_ 16
#define C_ 16
#define P_ 512
#define D_ 256

constexpr int HEADS = B_ * C_;     // 256
constexpr int PD    = P_ * D_;
constexpr float QSCALE = 0.0625f;  // D^-0.5
constexpr int CHW = 128 * 32 + 16 * 4;  // padded chunk words (16B pad / 8 rows)

typedef __attribute__((ext_vector_type(8))) short short8;   // 8 bf16
typedef __attribute__((ext_vector_type(4))) short short4_t; // 4 bf16
typedef __attribute__((ext_vector_type(4))) float floatx4;  // MFMA acc

#define MFMA_BF16 __builtin_amdgcn_mfma_f32_16x16x32_bf16

// fp32 -> (hi bf16, lo bf16) with x ~= hi + lo (residual ~2^-17 rel)
__device__ inline short2 split_hl(float x) {
    unsigned xb = __float_as_uint(x);
    unsigned hb = (xb + 0x8000u) & 0xFFFF0000u;
    float lf = x - __uint_as_float(hb);
    short2 r;
    r.x = (short)(hb >> 16);
    r.y = (short)((__float_as_uint(lf) + 0x8000u) >> 16);
    return r;
}
__device__ inline unsigned packsplit(float x) {
    short2 s = split_hl(x);
    return (unsigned)(unsigned short)s.x | ((unsigned)(unsigned short)s.y << 16);
}

// ---------------------------------------------------------------------------
// global_load_lds: LDS dest is wave-uniform base + lane*16 (linear);
// per-lane GLOBAL source carries the inverse slot-swizzle (rule 21).
// LDS rows padded 16B per 8-row group: word(r) = r*32 + (r>>3)*4.
// ---------------------------------------------------------------------------
__device__ inline void gload16(const unsigned* g, unsigned* l) {
    __builtin_amdgcn_global_load_lds(
        (__attribute__((address_space(1))) void*)(g),
        (__attribute__((address_space(3))) void*)(l), 16, 0, 0);
}
__device__ inline int ldsrow(int r) { return r * 32 + ((r >> 3) << 2); }

// 4-wave: stage 128x32-word tile, XOR slot swizzle + group pad.
__device__ inline void stage_sw(const unsigned* __restrict__ g, int gstride,
                                unsigned* lds, int tid) {
    int wv = tid >> 6, lane = tid & 63;
    int rsub = lane >> 3, slot = lane & 7;
#pragma unroll
    for (int it = 0; it < 4; ++it) {
        int r0 = it * 32 + wv * 8;        // wave-uniform, multiple of 8
        int row = r0 + rsub;
        const unsigned* src = g + (size_t)row * gstride + ((slot ^ (row & 7)) << 2);
        gload16(src, &lds[ldsrow(r0)]);
    }
}

// 8-wave version.
__device__ inline void stage_sw8(const unsigned* __restrict__ g, int gstride,
                                 unsigned* lds, int tid) {
    int wv = tid >> 6, lane = tid & 63;
    int rsub = lane >> 3, slot = lane & 7;
#pragma unroll
    for (int it = 0; it < 2; ++it) {
        int r0 = it * 64 + wv * 8;
        int row = r0 + rsub;
        const unsigned* src = g + (size_t)row * gstride + ((slot ^ (row & 7)) << 2);
        gload16(src, &lds[ldsrow(r0)]);
    }
}

// 8-wave V staging with k-granule permutation sg(g) = (g&1)*4 + (g>>1):
// makes the in-register P fragments (k = j*16+4*hi+r ownership) contract
// correctly against V without any P LDS round-trip.
__device__ inline void stage_sw8_v(const unsigned* __restrict__ g, int gstride,
                                   unsigned* lds, int tid) {
    int wv = tid >> 6, lane = tid & 63;
    int rsub = lane >> 3, slot = lane & 7;
#pragma unroll
    for (int it = 0; it < 2; ++it) {
        int r0 = it * 64 + wv * 8;
        int row = r0 + rsub;
        int sg = slot ^ (row & 7);
        sg = ((sg & 1) << 2) | (sg >> 1);
        const unsigned* src = g + (size_t)row * gstride + (sg << 2);
        gload16(src, &lds[ldsrow(r0)]);
    }
}

// unpack 8 packed pair-words (2 x uint4) -> hi short8 + lo short8 via v_perm
__device__ inline void unpack8(const uint4& a, const uint4& b, short8& h, short8& l) {
    union { unsigned u[4]; short8 s; } H, L;
    H.u[0] = __builtin_amdgcn_perm(a.y, a.x, 0x05040100u);
    L.u[0] = __builtin_amdgcn_perm(a.y, a.x, 0x07060302u);
    H.u[1] = __builtin_amdgcn_perm(a.w, a.z, 0x05040100u);
    L.u[1] = __builtin_amdgcn_perm(a.w, a.z, 0x07060302u);
    H.u[2] = __builtin_amdgcn_perm(b.y, b.x, 0x05040100u);
    L.u[2] = __builtin_amdgcn_perm(b.y, b.x, 0x07060302u);
    H.u[3] = __builtin_amdgcn_perm(b.w, b.z, 0x05040100u);
    L.u[3] = __builtin_amdgcn_perm(b.w, b.z, 0x07060302u);
    h = H.s; l = L.s;
}

// frag read from swizzled padded tile
__device__ inline void rdfrag_sw(const unsigned* lds, int r, int hi,
                                 short8& h, short8& l) {
    int base = ldsrow(r);
    int x = r & 7;
    const uint4 a = *reinterpret_cast<const uint4*>(&lds[base + ((((hi << 1))     ^ x) << 2)]);
    const uint4 b = *reinterpret_cast<const uint4*>(&lds[base + ((((hi << 1) | 1) ^ x) << 2)]);
    unpack8(a, b, h, l);
}

// frag read from padded [128][36] tile (register-staged A in proj)
__device__ inline void rdfrag_pad(const unsigned* lds, int r, int hi,
                                  short8& h, short8& l) {
    const uint4 a = *reinterpret_cast<const uint4*>(&lds[r * 36 + hi * 8]);
    const uint4 b = *reinterpret_cast<const uint4*>(&lds[r * 36 + hi * 8 + 4]);
    unpack8(a, b, h, l);
}

// ---------------------------------------------------------------------------
// S[b,p,d] = sum_c aw[c,p,d] * query[b,c,p,d]
// ---------------------------------------------------------------------------
__global__ __launch_bounds__(256) void k_sum_acw(const float* __restrict__ query,
                                                 const float* __restrict__ aw,
                                                 float* __restrict__ S) {
    int idx = blockIdx.x * 256 + threadIdx.x;
    int e = idx * 4;
    int d = e % D_;
    int p = (e / D_) % P_;
    int b = e / (D_ * P_);
    const float4* q4 = reinterpret_cast<const float4*>(query);
    const float4* a4 = reinterpret_cast<const float4*>(aw);
    int qbase = (((b * C_) * P_ + p) * D_ + d) >> 2;
    int abase = (p * D_ + d) >> 2;
    float4 acc = {0.f, 0.f, 0.f, 0.f};
#pragma unroll
    for (int c = 0; c < C_; ++c) {
        float4 qv = q4[qbase + c * (PD / 4)];
        float4 av = a4[abase + c * (PD / 4)];
        acc.x += qv.x * av.x;
        acc.y += qv.y * av.y;
        acc.z += qv.z * av.z;
        acc.w += qv.w * av.w;
    }
    reinterpret_cast<float4*>(S)[idx] = acc;
}

// ---------------------------------------------------------------------------
// Pack + transpose weights: W2t[wsel][c][n][k] pair-words from W[c][k][n] fp32
// ---------------------------------------------------------------------------
__global__ __launch_bounds__(256) void k_wpack(const float* __restrict__ Wq,
                                               const float* __restrict__ Wk,
                                               const float* __restrict__ Wv,
                                               unsigned* __restrict__ W2t) {
    __shared__ float tile[64][68];
    int wsel = blockIdx.z / C_;
    int c    = blockIdx.z % C_;
    int k0 = blockIdx.x * 64, n0 = blockIdx.y * 64;
    const float* Wsrc = wsel == 0 ? Wq : (wsel == 1 ? Wk : Wv);
    int tid = threadIdx.x;
#pragma unroll
    for (int it = 0; it < 4; ++it) {
        int idx = tid + it * 256;
        int kr = idx >> 4, nc = (idx & 15) * 4;
        float4 f = *reinterpret_cast<const float4*>(
            &Wsrc[(size_t)(c * D_ + k0 + kr) * D_ + n0 + nc]);
        *reinterpret_cast<float4*>(&tile[kr][nc]) = f;
    }
    __syncthreads();
#pragma unroll
    for (int it = 0; it < 4; ++it) {
        int idx = tid + it * 256;
        int nr = idx >> 4, kc = (idx & 15) * 4;
        uint4 u;
        u.x = packsplit(tile[kc + 0][nr]);
        u.y = packsplit(tile[kc + 1][nr]);
        u.z = packsplit(tile[kc + 2][nr]);
        u.w = packsplit(tile[kc + 3][nr]);
        *reinterpret_cast<uint4*>(
            &W2t[((size_t)(wsel * C_ + c) * D_ + n0 + nr) * D_ + k0 + kc]) = u;
    }
}

// ---------------------------------------------------------------------------
// Fused split-bf16 MFMA projection, 2-phase double-buffered pipeline.
// ---------------------------------------------------------------------------
__global__ __launch_bounds__(256) void k_proj_mfma(
    const float* __restrict__ query, const float* __restrict__ aw,
    const float* __restrict__ S, const unsigned* __restrict__ W2t,
    const float* __restrict__ bq, const float* __restrict__ bk,
    const float* __restrict__ bv,
    unsigned* __restrict__ Q2, unsigned* __restrict__ K2,
    unsigned* __restrict__ V2t, int head0) {
    __shared__ unsigned Aw[2][128 * 36];
    __shared__ unsigned Bw[2][CHW];
    int tid = threadIdx.x;
    int lane = tid & 63, wv = tid >> 6;
    int wm = wv >> 1, wn = wv & 1;
    int ln = lane & 15, hi = lane >> 4, quad4 = hi * 4;
    int n0 = blockIdx.x * 128;
    int m0 = blockIdx.y * 128;
    int lh = blockIdx.z / 3, oid = blockIdx.z % 3;
    int hd = head0 + lh;
    int b = hd / C_, c = hd % C_;
    const unsigned* Wt = W2t + (size_t)(oid * C_ + c) * D_ * D_;

    int arow = tid >> 3, ack = (tid & 7) * 4;

    floatx4 acc[4][4] = {};

    stage_sw(Wt + (size_t)n0 * D_, D_, &Bw[0][0], tid);
#pragma unroll
    for (int it = 0; it < 4; ++it) {
        int row = arow + it * 32;
        float4 qv = *reinterpret_cast<const float4*>(
            &query[(size_t)(hd * P_ + m0 + row) * D_ + ack]);
        float x0, x1, x2, x3;
        if (oid == 0) {
            x0 = qv.x; x1 = qv.y; x2 = qv.z; x3 = qv.w;
        } else {
            float4 sv = *reinterpret_cast<const float4*>(
                &S[(size_t)(b * P_ + m0 + row) * D_ + ack]);
            float4 av = *reinterpret_cast<const float4*>(
                &aw[(size_t)(c * P_ + m0 + row) * D_ + ack]);
            x0 = sv.x - av.x * qv.x; x1 = sv.y - av.y * qv.y;
            x2 = sv.z - av.z * qv.z; x3 = sv.w - av.w * qv.w;
        }
        uint4 u;
        u.x = packsplit(x0); u.y = packsplit(x1);
        u.z = packsplit(x2); u.w = packsplit(x3);
        *reinterpret_cast<uint4*>(&Aw[0][row * 36 + ack]) = u;
    }
    __syncthreads();

    int cur = 0;
    for (int t = 0; t < 8; ++t) {
        int nx = cur ^ 1;
        bool pf = t < 7;
        int kk = (t + 1) * 32;
        if (pf) stage_sw(Wt + (size_t)n0 * D_ + kk, D_, &Bw[nx][0], tid);
        float4 qv[4], sv[4], av[4];
        if (pf) {
#pragma unroll
            for (int it = 0; it < 4; ++it) {
                int row = arow + it * 32;
                qv[it] = *reinterpret_cast<const float4*>(
                    &query[(size_t)(hd * P_ + m0 + row) * D_ + kk + ack]);
                if (oid != 0) {
                    sv[it] = *reinterpret_cast<const float4*>(
                        &S[(size_t)(b * P_ + m0 + row) * D_ + kk + ack]);
                    av[it] = *reinterpret_cast<const float4*>(
                        &aw[(size_t)(c * P_ + m0 + row) * D_ + kk + ack]);
                }
            }
        }
        short8 ah[4], alo[4], bh[4], blo[4];
#pragma unroll
        for (int i = 0; i < 4; ++i) {
            rdfrag_pad(&Aw[cur][0], wm * 64 + i * 16 + ln, hi, ah[i], alo[i]);
            rdfrag_sw(&Bw[cur][0], wn * 64 + i * 16 + ln, hi, bh[i], blo[i]);
        }
#pragma unroll
        for (int i = 0; i < 4; ++i)
#pragma unroll
            for (int j = 0; j < 4; ++j) {
                acc[i][j] = MFMA_BF16(ah[i], bh[j], acc[i][j], 0, 0, 0);
                acc[i][j] = MFMA_BF16(ah[i], blo[j], acc[i][j], 0, 0, 0);
                acc[i][j] = MFMA_BF16(alo[i], bh[j], acc[i][j], 0, 0, 0);
            }
        if (pf) {
#pragma unroll
            for (int it = 0; it < 4; ++it) {
                int row = arow + it * 32;
                float x0, x1, x2, x3;
                if (oid == 0) {
                    x0 = qv[it].x; x1 = qv[it].y; x2 = qv[it].z; x3 = qv[it].w;
                } else {
                    x0 = sv[it].x - av[it].x * qv[it].x;
                    x1 = sv[it].y - av[it].y * qv[it].y;
                    x2 = sv[it].z - av[it].z * qv[it].z;
                    x3 = sv[it].w - av[it].w * qv[it].w;
                }
                uint4 u;
                u.x = packsplit(x0); u.y = packsplit(x1);
                u.z = packsplit(x2); u.w = packsplit(x3);
                *reinterpret_cast<uint4*>(&Aw[nx][row * 36 + ack]) = u;
            }
        }
        __syncthreads();
        cur = nx;
    }

    const float* bias = oid == 0 ? bq : (oid == 1 ? bk : bv);
    float scale = oid == 0 ? QSCALE : 1.0f;
#pragma unroll
    for (int j = 0; j < 4; ++j) {
        int n_g = n0 + wn * 64 + j * 16 + ln;
        float bb = bias[c * D_ + n_g];
#pragma unroll
        for (int i = 0; i < 4; ++i) {
            int p0 = m0 + wm * 64 + i * 16 + quad4;
            if (oid == 2) {
                uint4 u;
                u.x = packsplit(fmaxf(acc[i][j][0] + bb, 0.f));
                u.y = packsplit(fmaxf(acc[i][j][1] + bb, 0.f));
                u.z = packsplit(fmaxf(acc[i][j][2] + bb, 0.f));
                u.w = packsplit(fmaxf(acc[i][j][3] + bb, 0.f));
                *reinterpret_cast<uint4*>(&V2t[(size_t)(lh * D_ + n_g) * P_ + p0]) = u;
            } else {
                unsigned* dst = oid == 0 ? Q2 : K2;
#pragma unroll
                for (int r = 0; r < 4; ++r) {
                    float v = fmaxf(acc[i][j][r] + bb, 0.f) * scale;
                    dst[(size_t)(lh * P_ + p0 + r) * D_ + n_g] = packsplit(v);
                }
            }
        }
    }
}

// ---------------------------------------------------------------------------
// Fused flash attention, swapped-operand QK^T + in-register P.
// Block = 512 threads (8 waves), one head x 128 Q-rows; 4 KV-tiles of 128.
// QK^T computes mfma(K,Q) so lane (hi,ln) owns S[k=j*16+4hi+r][q=ln]:
// softmax is 2 shuffles; the owned P values form the PV A-fragment directly
// under k-permutation sigma(8hi+t) = (t>=4)*16+4hi+(t&3), which is folded
// into V's staging granule order (stage_sw8_v). P never touches LDS.
// LDS = 4 padded chunks (~65 KB) -> 2 blocks/CU.
// ---------------------------------------------------------------------------
__global__ __launch_bounds__(512, 4) void k_attn(
    const unsigned* __restrict__ Q2, const unsigned* __restrict__ K2,
    const unsigned* __restrict__ V2t, float* __restrict__ O, int head0) {
    __shared__ unsigned chunk[4][CHW];
    int tid = threadIdx.x;
    int lane = tid & 63, wv = tid >> 6;
    int ln = lane & 15, hi = lane >> 4;
    int lh = blockIdx.x;
    int m0 = blockIdx.y * 128;
    int hd = head0 + lh;
    const unsigned* gq = Q2 + ((size_t)lh * P_ + m0) * D_;
    const unsigned* gk = K2 + (size_t)lh * P_ * D_;
    const unsigned* gv = V2t + (size_t)lh * D_ * P_;

    floatx4 o[16] = {};
    float m_ = -INFINITY, l_ = 0.f;

    // prologue: QK tile kk=0 of kv=0
    stage_sw8(gq, D_, chunk[0], tid);
    stage_sw8(gk, D_, chunk[2], tid);
    __syncthreads();
    int cur = 0;

    for (int kv = 0; kv < 4; ++kv) {
        // ---- QK^T (swapped): s_[j] rows = k-local, cols = q
        floatx4 s_[8] = {};
        for (int kk = 0; kk < 8; ++kk) {
            int nx = cur ^ 1;
            if (kk < 7) {
                stage_sw8(gq + (kk + 1) * 32, D_, chunk[nx], tid);
                stage_sw8(gk + (size_t)(kv * 128) * D_ + (kk + 1) * 32, D_,
                          chunk[2 + nx], tid);
            } else {
                stage_sw8_v(gv + kv * 128, P_, chunk[nx], tid);
                stage_sw8_v(gv + (size_t)128 * P_ + kv * 128, P_, chunk[2 + nx], tid);
            }
            short8 qh, ql, kh, kl;
            rdfrag_sw(chunk[cur], wv * 16 + ln, hi, qh, ql);
            __builtin_amdgcn_s_setprio(1);
#pragma unroll
            for (int j = 0; j < 8; ++j) {
                rdfrag_sw(chunk[2 + cur], j * 16 + ln, hi, kh, kl);
                s_[j] = MFMA_BF16(kh, qh, s_[j], 0, 0, 0);
                s_[j] = MFMA_BF16(kh, ql, s_[j], 0, 0, 0);
                s_[j] = MFMA_BF16(kl, qh, s_[j], 0, 0, 0);
            }
            __builtin_amdgcn_s_setprio(0);
            __syncthreads();
            cur = nx;
        }

        // ---- online softmax for q = wv*16+ln (lane-local row)
        float mx = s_[0][0];
#pragma unroll
        for (int j = 0; j < 8; ++j)
#pragma unroll
            for (int r = 0; r < 4; ++r) mx = fmaxf(mx, s_[j][r]);
        mx = fmaxf(mx, __shfl_xor(mx, 16));
        mx = fmaxf(mx, __shfl_xor(mx, 32));
        float mn = fmaxf(m_, mx);
        float sc = __expf(m_ - mn);
        m_ = mn;

        // P = exp(s-m): pack straight into PV A-fragments (no LDS)
        float rs = 0.f;
        short8 pah[4], pal[4];
#pragma unroll
        for (int kq = 0; kq < 4; ++kq)
#pragma unroll
            for (int t = 0; t < 4; ++t) {
                float pa = __expf(s_[2 * kq][t] - m_);
                float pb = __expf(s_[2 * kq + 1][t] - m_);
                rs += pa + pb;
                short2 sa = split_hl(pa), sb = split_hl(pb);
                pah[kq][t] = sa.x;     pal[kq][t] = sa.y;
                pah[kq][4 + t] = sb.x; pal[kq][4 + t] = sb.y;
            }
        rs += __shfl_xor(rs, 16);
        rs += __shfl_xor(rs, 32);
        l_ = l_ * sc + rs;

        // rescale O (rows are q = 4hi+r -> broadcast sc from lane ln'=4hi+r)
        float scr[4];
#pragma unroll
        for (int r = 0; r < 4; ++r)
            scr[r] = __shfl(sc, (lane & 48) | (hi * 4 + r));
#pragma unroll
        for (int n = 0; n < 16; ++n)
#pragma unroll
            for (int r = 0; r < 4; ++r) o[n][r] *= scr[r];

        // ---- PV: 4 k-steps of 32; A = in-register P frags
#pragma unroll
        for (int kq = 0; kq < 4; ++kq) {
            int nx = cur ^ 1;
            if (kq < 3) {
                stage_sw8_v(gv + kv * 128 + (kq + 1) * 32, P_, chunk[nx], tid);
                stage_sw8_v(gv + (size_t)128 * P_ + kv * 128 + (kq + 1) * 32, P_,
                            chunk[2 + nx], tid);
            } else if (kv < 3) {
                stage_sw8(gq, D_, chunk[nx], tid);
                stage_sw8(gk + (size_t)((kv + 1) * 128) * D_, D_, chunk[2 + nx], tid);
            }
            __builtin_amdgcn_s_setprio(1);
#pragma unroll
            for (int n = 0; n < 16; ++n) {
                short8 vh, vl;
                const unsigned* vb = (n < 8) ? chunk[cur] : chunk[2 + cur];
                rdfrag_sw(vb, (n & 7) * 16 + ln, hi, vh, vl);
                o[n] = MFMA_BF16(pah[kq], vh, o[n], 0, 0, 0);
                o[n] = MFMA_BF16(pah[kq], vl, o[n], 0, 0, 0);
                o[n] = MFMA_BF16(pal[kq], vh, o[n], 0, 0, 0);
            }
            __builtin_amdgcn_s_setprio(0);
            __syncthreads();
            cur = nx;
        }
    }

    // ---- epilogue: divide by row sum (broadcast from lane ln'=4hi+r)
    float inv = 1.0f / l_;
    float invr[4];
#pragma unroll
    for (int r = 0; r < 4; ++r)
        invr[r] = __shfl(inv, (lane & 48) | (hi * 4 + r));
#pragma unroll
    for (int n = 0; n < 16; ++n) {
        int col = n * 16 + ln;
#pragma unroll
        for (int r = 0; r < 4; ++r) {
            int row = m0 + wv * 16 + hi * 4 + r;
            O[((size_t)hd * P_ + row) * D_ + col] = o[n][r] * invr[r];
        }
    }
}

// ---------------------------------------------------------------------------
extern "C" void kernel_launch(void* const* d_in, const int* in_sizes, int n_in,
                              void* d_out, int out_size, void* d_ws, size_t ws_size,
                              hipStream_t stream) {
    (void)in_sizes; (void)n_in; (void)out_size;
    const float* query = (const float*)d_in[0];
    const float* aw    = (const float*)d_in[1];
    const float* Wq    = (const float*)d_in[2];
    const float* Wk    = (const float*)d_in[3];
    const float* Wv    = (const float*)d_in[4];
    const float* bq    = (const float*)d_in[5];
    const float* bk    = (const float*)d_in[6];
    const float* bv    = (const float*)d_in[7];
    float* out = (float*)d_out;

    char* ws = (char*)d_ws;
    const size_t s_words   = (size_t)B_ * P_ * D_;
    const size_t w2t_words = (size_t)3 * C_ * D_ * D_;
    const size_t fixed_bytes = (s_words + w2t_words) * 4;
    const size_t per_head_bytes = (size_t)3 * P_ * D_ * 4;  // Q2,K2,V2t
    size_t avail = ws_size > fixed_bytes ? ws_size - fixed_bytes : 0;
    int H = (int)(avail / per_head_bytes);
    if (H < 1) H = 1;
    if (H > HEADS) H = HEADS;

    float*    S   = (float*)ws;
    unsigned* W2t = (unsigned*)(ws + s_words * 4);
    unsigned* Q2  = (unsigned*)(ws + fixed_bytes);
    unsigned* K2  = Q2 + (size_t)H * P_ * D_;
    unsigned* V2t = K2 + (size_t)H * P_ * D_;

    k_sum_acw<<<(B_ * P_ * D_ / 4) / 256, 256, 0, stream>>>(query, aw, S);
    k_wpack<<<dim3(D_ / 64, D_ / 64, 3 * C_), 256, 0, stream>>>(Wq, Wk, Wv, W2t);

    for (int head0 = 0; head0 < HEADS; head0 += H) {
        int Hc = HEADS - head0 < H ? HEADS - head0 : H;
        k_proj_mfma<<<dim3(D_ / 128, P_ / 128, 3 * Hc), 256, 0, stream>>>(
            query, aw, S, W2t, bq, bk, bv, Q2, K2, V2t, head0);
        k_attn<<<dim3(Hc, P_ / 128), 512, 0, stream>>>(Q2, K2, V2t, out, head0);
    }
}